// Round 7
// baseline (622.770 us; speedup 1.0000x reference)
//
#include <hip/hip_runtime.h>
#include <hip/hip_bf16.h>
#include <stdint.h>
#include <stddef.h>

#define NN 8192
#define DD 128
#define PADW 136    // LDS row stride (bf16): 272 B, staggers banks
#define PANELS 64   // j-panels (grid.x)

typedef __attribute__((ext_vector_type(8))) short bf16x8;
typedef __attribute__((ext_vector_type(4))) float f32x4;

static __device__ __forceinline__ unsigned short f2bf(float x) {
  __hip_bfloat16 h = __float2bfloat16(x);
  return *(unsigned short*)&h;
}

// ---------------------------------------------------------------------------
// Kernel 1: row-normalize features (fp32) and cast to bf16. One wave per row.
// ---------------------------------------------------------------------------
__global__ __launch_bounds__(256) void normalize_kernel(
    const float* __restrict__ f, __hip_bfloat16* __restrict__ fn) {
  const int wave = threadIdx.x >> 6;
  const int lane = threadIdx.x & 63;
  const int row = blockIdx.x * 4 + wave;
  const float2 v = ((const float2*)(f + (size_t)row * DD))[lane];
  float ss = v.x * v.x + v.y * v.y;
#pragma unroll
  for (int m = 1; m < 64; m <<= 1) ss += __shfl_xor(ss, m, 64);
  const float inv = 1.0f / fmaxf(sqrtf(ss), 1e-8f);
  __hip_bfloat162 o;
  o.x = __float2bfloat16(v.x * inv);
  o.y = __float2bfloat16(v.y * inv);
  ((__hip_bfloat162*)(fn + (size_t)row * DD))[lane] = o;
}

// ---------------------------------------------------------------------------
// Kernel 2: 64x128 sim tile per 512-thread block, tuned for OCCUPANCY:
// each of 8 warps computes a lean 16x64 GEMM slab (acc[4] = 16 regs) so the
// whole kernel fits 64 VGPR -> 4 blocks/CU x 8 waves = 32 waves/CU streaming
// (2x round-2). All mask loads are issued BEFORE the barrier (acc regs dead),
// so their HBM latency hides under other warps' MFMA tails + the barrier.
//   Phase 1: GEMM (fragments straight from L2; fn is 2 MB).
//   Phase 2: exp(sim/T) -> LDS bf16 (17 KB).
//   Prefetch: 8 x int4 mask loads for both phase-3 iterations.
//   Phase 3: pure LDS+VALU masked accumulation; deferred 16-lane reduce.
//   Epilogue: plain stores into 64-panel partial arrays (atomic-free).
// ---------------------------------------------------------------------------
template <bool DIAG>
__global__ __launch_bounds__(512, 8) void ssnt_main(
    const __hip_bfloat16* __restrict__ fn,
    const int* __restrict__ pmask,
    const int* __restrict__ nmask,
    float* __restrict__ pP, float* __restrict__ nP, float* __restrict__ cP) {
  __shared__ __hip_bfloat16 sim[64 * PADW];  // 17 KB

  const int tid = threadIdx.x;
  const int lane = tid & 63;
  const int quad = lane >> 4;
  const int l16 = lane & 15;
  const int w = tid >> 6;   // warp 0..7
  const int wy = w >> 1;    // row slab 0..3 (16 rows each)
  const int wx = w & 1;     // col slab 0..1 (64 cols each)

  const int I0g = blockIdx.y * 64;
  const int J0g = blockIdx.x * 128;
  const int I0w = I0g + wy * 16;
  const int J0w = J0g + wx * 64;

  // ---- Phase 1: GEMM. Fragment (nt,r): i = I0w + l16, j = J0w + nt*16+quad*4+r
  f32x4 acc[4] = {};
#pragma unroll
  for (int kt = 0; kt < 4; ++kt) {
    const int ko = kt * 32 + quad * 8;
    const bf16x8 aF = *(const bf16x8*)(fn + (size_t)(I0w + l16) * DD + ko);
    bf16x8 bF[4];
#pragma unroll
    for (int nt = 0; nt < 4; ++nt)
      bF[nt] = *(const bf16x8*)(fn + (size_t)(J0w + nt * 16 + l16) * DD + ko);
#pragma unroll
    for (int nt = 0; nt < 4; ++nt)
      acc[nt] = __builtin_amdgcn_mfma_f32_16x16x32_bf16(
          bF[nt], aF, acc[nt], 0, 0, 0);  // SWAPPED operands
  }

  // ---- Phase 2: exp -> LDS (bf16) ----
  const float tinv = 1.0f / 0.07f;
  {
    const int row = wy * 16 + l16;
#pragma unroll
    for (int nt = 0; nt < 4; ++nt) {
      const int col = wx * 64 + nt * 16 + quad * 4;
      ushort4 w4;
      w4.x = f2bf(__expf(acc[nt][0] * tinv));
      w4.y = f2bf(__expf(acc[nt][1] * tinv));
      w4.z = f2bf(__expf(acc[nt][2] * tinv));
      w4.w = f2bf(__expf(acc[nt][3] * tinv));
      *(ushort4*)(sim + row * PADW + col) = w4;
    }
  }

  // ---- Prefetch ALL mask loads (acc is dead; 32 regs of payload).
  // Issued before the barrier: HBM latency overlaps other warps' MFMA + bar.
  const int rGrp = tid >> 4;  // 0..31
  const int cl = tid & 15;    // 8 cols each
  int4 pm[2][2], nm[2][2];
#pragma unroll
  for (int it = 0; it < 2; ++it) {
    const size_t mOff = (size_t)(I0g + it * 32 + rGrp) * NN + J0g + cl * 8;
    pm[it][0] = *(const int4*)(pmask + mOff);
    pm[it][1] = *(const int4*)(pmask + mOff + 4);
    nm[it][0] = *(const int4*)(nmask + mOff);
    nm[it][1] = *(const int4*)(nmask + mOff + 4);
  }

  __syncthreads();

  // ---- Phase 3: pure LDS+VALU masked accumulation ----
  float accP[2], accQ[2], accC[2];
#pragma unroll
  for (int it = 0; it < 2; ++it) {
    const int rLoc = it * 32 + rGrp;
    const bf16x8 ev = *(const bf16x8*)(sim + rLoc * PADW + cl * 8);
    int pm8[8], nm8[8];
    *(int4*)&pm8[0] = pm[it][0]; *(int4*)&pm8[4] = pm[it][1];
    *(int4*)&nm8[0] = nm[it][0]; *(int4*)&nm8[4] = nm[it][1];
    const int dj = DIAG ? ((I0g + rLoc) - (J0g + cl * 8)) : -1;
    float p = 0.f, q = 0.f;
    int c = 0;
#pragma unroll
    for (int r = 0; r < 8; ++r) {
      int pmv = pm8[r];
      int nmv = nm8[r];
      if (DIAG) {
        if (r == dj) { pmv = 0; nmv = 0; }  // zero self-contrast
      }
      const float e = __uint_as_float(((unsigned int)(unsigned short)ev[r]) << 16);
      p = fmaf(e, (float)pmv, p);
      q = fmaf(e, (float)nmv, q);
      c += pmv;
    }
    accP[it] = p; accQ[it] = q; accC[it] = (float)c;
  }

  // ---- deferred 16-lane reduce (6 independent chains), panel stores ----
#pragma unroll
  for (int m = 1; m < 16; m <<= 1) {
#pragma unroll
    for (int it = 0; it < 2; ++it) {
      accP[it] += __shfl_xor(accP[it], m, 64);
      accQ[it] += __shfl_xor(accQ[it], m, 64);
      accC[it] += __shfl_xor(accC[it], m, 64);
    }
  }
#pragma unroll
  for (int it = 0; it < 2; ++it) {
    const int iG = I0g + it * 32 + rGrp;
    const size_t po = (size_t)blockIdx.x * NN + iG;
    if (cl == 0)      pP[po] = accP[it];
    else if (cl == 1) nP[po] = accQ[it];
    else if (cl == 2) cP[po] = accC[it];
  }
}

// ---------------------------------------------------------------------------
// Kernel 3a: reduce panels per row, per-row loss term, block sum -> blkSum[32]
// ---------------------------------------------------------------------------
__global__ __launch_bounds__(256) void finalize1(
    const float* __restrict__ pP, const float* __restrict__ nP,
    const float* __restrict__ cP, float* __restrict__ blkSum) {
  const int r = blockIdx.x * 256 + threadIdx.x;
  float p = 0.f, q = 0.f, c = 0.f;
#pragma unroll 4
  for (int k = 0; k < PANELS; ++k) {
    p += pP[(size_t)k * NN + r];
    q += nP[(size_t)k * NN + r];
    c += cP[(size_t)k * NN + r];
  }
  float s = logf(p / (p + q)) / c;
#pragma unroll
  for (int m = 1; m < 64; m <<= 1) s += __shfl_xor(s, m, 64);
  __shared__ float ws4[4];
  if ((threadIdx.x & 63) == 0) ws4[threadIdx.x >> 6] = s;
  __syncthreads();
  if (threadIdx.x == 0)
    blkSum[blockIdx.x] = ws4[0] + ws4[1] + ws4[2] + ws4[3];
}

// Kernel 3b: final 32-value sum -> loss
__global__ void finalize2(const float* __restrict__ blkSum,
                          float* __restrict__ out) {
  float s = (threadIdx.x < NN / 256) ? blkSum[threadIdx.x] : 0.f;
#pragma unroll
  for (int m = 1; m < 64; m <<= 1) s += __shfl_xor(s, m, 64);
  if (threadIdx.x == 0) out[0] = -s / (float)NN;
}

// ---------------------------------------------------------------------------
// Dispatcher: diagonal blocks (by>>1 == bx) take the DIAG template; rather
// than branch per-block inside, launch one grid and branch on a uniform
// predicate (cheap, wave-uniform). Two instantiations share the code path.
// ---------------------------------------------------------------------------
__global__ __launch_bounds__(512, 8) void ssnt_dispatch(
    const __hip_bfloat16* __restrict__ fn,
    const int* __restrict__ pmask,
    const int* __restrict__ nmask,
    float* __restrict__ pP, float* __restrict__ nP, float* __restrict__ cP);

extern "C" void kernel_launch(void* const* d_in, const int* in_sizes, int n_in,
                              void* d_out, int out_size, void* d_ws, size_t ws_size,
                              hipStream_t stream) {
  const float* features = (const float*)d_in[0];
  const int* pmask = (const int*)d_in[1];
  const int* nmask = (const int*)d_in[2];
  float* out = (float*)d_out;

  char* ws = (char*)d_ws;
  __hip_bfloat16* fn = (__hip_bfloat16*)ws;  // 2 MB
  float* pP = (float*)(ws + (size_t)NN * DD * sizeof(__hip_bfloat16));
  float* nP = pP + (size_t)PANELS * NN;      // 3 x 2 MB panels
  float* cP = nP + (size_t)PANELS * NN;
  float* blkSum = cP + (size_t)PANELS * NN;  // 128 B

  normalize_kernel<<<NN / 4, 256, 0, stream>>>(features, fn);
  // DIAG=true instantiation covers every block; the dj test is wave-uniform
  // false for off-diagonal blocks (predicated out, ~zero cost), avoiding a
  // second launch or divergent template dispatch.
  ssnt_main<true><<<dim3(NN / 128, NN / 64), 512, 0, stream>>>(
      fn, pmask, nmask, pP, nP, cP);
  finalize1<<<NN / 256, 256, 0, stream>>>(pP, nP, cP, blkSum);
  finalize2<<<1, 64, 0, stream>>>(blkSum, out);
}

// Round 8
// 597.003 us; speedup vs baseline: 1.0432x; 1.0432x over previous
//
#include <hip/hip_runtime.h>
#include <hip/hip_bf16.h>
#include <stdint.h>
#include <stddef.h>

#define NN 8192
#define DD 128
#define PADW 72     // LDS row stride (bf16) for 64-col tile: 144 B
#define PANELS 128  // j-panels (grid.x): one partial array per 64-col panel

typedef __attribute__((ext_vector_type(8))) short bf16x8;
typedef __attribute__((ext_vector_type(4))) float f32x4;

static __device__ __forceinline__ unsigned short f2bf(float x) {
  __hip_bfloat16 h = __float2bfloat16(x);
  return *(unsigned short*)&h;
}

// ---------------------------------------------------------------------------
// Kernel 1: row-normalize features (fp32) and cast to bf16. One wave per row.
// ---------------------------------------------------------------------------
__global__ __launch_bounds__(256) void normalize_kernel(
    const float* __restrict__ f, __hip_bfloat16* __restrict__ fn) {
  const int wave = threadIdx.x >> 6;
  const int lane = threadIdx.x & 63;
  const int row = blockIdx.x * 4 + wave;
  const float2 v = ((const float2*)(f + (size_t)row * DD))[lane];
  float ss = v.x * v.x + v.y * v.y;
#pragma unroll
  for (int m = 1; m < 64; m <<= 1) ss += __shfl_xor(ss, m, 64);
  const float inv = 1.0f / fmaxf(sqrtf(ss), 1e-8f);
  __hip_bfloat162 o;
  o.x = __float2bfloat16(v.x * inv);
  o.y = __float2bfloat16(v.y * inv);
  ((__hip_bfloat162*)(fn + (size_t)row * DD))[lane] = o;
}

// ---------------------------------------------------------------------------
// Phase 3: row-major masked accumulation from LDS, loads in-loop (NO explicit
// prefetch payload — round-7 lesson: big reg payloads + bounds => spill; MLP
// comes from 24-32 lean waves/CU instead).
// Thread (rGrp=tid>>3, cl=tid&7): rows it*32+rGrp, cols [cl*8, cl*8+8).
// ---------------------------------------------------------------------------
template <bool DIAG>
static __device__ __forceinline__ void phase3(
    const __hip_bfloat16* __restrict__ sim,
    const int* __restrict__ pmask, const int* __restrict__ nmask,
    int I0g, int J0g, int rGrp, int cl,
    float* __restrict__ accP, float* __restrict__ accQ,
    float* __restrict__ accC) {
#pragma unroll
  for (int it = 0; it < 4; ++it) {
    const int rLoc = it * 32 + rGrp;
    const size_t mOff = (size_t)(I0g + rLoc) * NN + J0g + cl * 8;
    const int4 pa = *(const int4*)(pmask + mOff);
    const int4 pb = *(const int4*)(pmask + mOff + 4);
    const int4 na = *(const int4*)(nmask + mOff);
    const int4 nb = *(const int4*)(nmask + mOff + 4);
    const bf16x8 ev = *(const bf16x8*)(sim + rLoc * PADW + cl * 8);
    int pm8[8], nm8[8];
    *(int4*)&pm8[0] = pa; *(int4*)&pm8[4] = pb;
    *(int4*)&nm8[0] = na; *(int4*)&nm8[4] = nb;
    const int dj = DIAG ? ((I0g + rLoc) - (J0g + cl * 8)) : -1;
    float p = 0.f, q = 0.f;
    int c = 0;
#pragma unroll
    for (int r = 0; r < 8; ++r) {
      int pm = pm8[r];
      int nm = nm8[r];
      if (DIAG) {
        if (r == dj) { pm = 0; nm = 0; }  // zero self-contrast
      }
      const float e = __uint_as_float(((unsigned int)(unsigned short)ev[r]) << 16);
      p = fmaf(e, (float)pm, p);
      q = fmaf(e, (float)nm, q);
      c += pm;
    }
    accP[it] = p; accQ[it] = q; accC[it] = (float)c;
  }
}

// ---------------------------------------------------------------------------
// Kernel 2: 128x64 sim tile per 256-thread block — round-2 structure at 2x
// occupancy. LDS 18 KB -> 8 blocks/CU; per-warp GEMM slab 32x64 (acc[2][4] =
// 32 regs, lean); soft __launch_bounds__(256,6) so the allocator is free
// (~84 cap) and cannot be forced into scratch.
// ---------------------------------------------------------------------------
template <bool DIAG>
static __device__ __forceinline__ void tile_body(
    const __hip_bfloat16* __restrict__ fn,
    const int* __restrict__ pmask, const int* __restrict__ nmask,
    float* __restrict__ pP, float* __restrict__ nP, float* __restrict__ cP,
    __hip_bfloat16* __restrict__ sim) {
  const int tid = threadIdx.x;
  const int lane = tid & 63;
  const int quad = lane >> 4;
  const int l16 = lane & 15;
  const int w = tid >> 6;  // warp 0..3: rows [w*32, w*32+32)

  const int I0g = blockIdx.y * 128;
  const int J0g = blockIdx.x * 64;
  const int I0w = I0g + w * 32;

  // ---- Phase 1: GEMM. Fragment (mt,nt,r):
  //   i = I0w + mt*16 + l16,  j = J0g + nt*16 + quad*4 + r
  f32x4 acc[2][4] = {};
#pragma unroll
  for (int kt = 0; kt < 4; ++kt) {
    const int ko = kt * 32 + quad * 8;
    bf16x8 aF[2], bF[4];
#pragma unroll
    for (int mt = 0; mt < 2; ++mt)
      aF[mt] = *(const bf16x8*)(fn + (size_t)(I0w + mt * 16 + l16) * DD + ko);
#pragma unroll
    for (int nt = 0; nt < 4; ++nt)
      bF[nt] = *(const bf16x8*)(fn + (size_t)(J0g + nt * 16 + l16) * DD + ko);
#pragma unroll
    for (int mt = 0; mt < 2; ++mt)
#pragma unroll
      for (int nt = 0; nt < 4; ++nt)
        acc[mt][nt] = __builtin_amdgcn_mfma_f32_16x16x32_bf16(
            bF[nt], aF[mt], acc[mt][nt], 0, 0, 0);  // SWAPPED operands
  }

  // ---- Phase 2: exp -> LDS (bf16) ----
  const float tinv = 1.0f / 0.07f;
#pragma unroll
  for (int mt = 0; mt < 2; ++mt) {
    const int row = w * 32 + mt * 16 + l16;
#pragma unroll
    for (int nt = 0; nt < 4; ++nt) {
      const int col = nt * 16 + quad * 4;
      ushort4 w4;
      w4.x = f2bf(__expf(acc[mt][nt][0] * tinv));
      w4.y = f2bf(__expf(acc[mt][nt][1] * tinv));
      w4.z = f2bf(__expf(acc[mt][nt][2] * tinv));
      w4.w = f2bf(__expf(acc[mt][nt][3] * tinv));
      *(ushort4*)(sim + row * PADW + col) = w4;
    }
  }
  __syncthreads();

  // ---- Phase 3 + deferred reduce + panel stores ----
  const int rGrp = tid >> 3;  // 0..31
  const int cl = tid & 7;     // 0..7, 8 cols each
  float accP[4], accQ[4], accC[4];
  phase3<DIAG>(sim, pmask, nmask, I0g, J0g, rGrp, cl, accP, accQ, accC);

#pragma unroll
  for (int m = 1; m < 8; m <<= 1) {
#pragma unroll
    for (int it = 0; it < 4; ++it) {
      accP[it] += __shfl_xor(accP[it], m, 64);
      accQ[it] += __shfl_xor(accQ[it], m, 64);
      accC[it] += __shfl_xor(accC[it], m, 64);
    }
  }
#pragma unroll
  for (int it = 0; it < 4; ++it) {
    const int iG = I0g + it * 32 + rGrp;
    const size_t po = (size_t)blockIdx.x * NN + iG;
    if (cl == 0)      pP[po] = accP[it];
    else if (cl == 1) nP[po] = accQ[it];
    else if (cl == 2) cP[po] = accC[it];
  }
}

__global__ __launch_bounds__(256, 6) void ssnt_main(
    const __hip_bfloat16* __restrict__ fn,
    const int* __restrict__ pmask,
    const int* __restrict__ nmask,
    float* __restrict__ pP, float* __restrict__ nP, float* __restrict__ cP) {
  __shared__ __hip_bfloat16 sim[128 * PADW];  // 18 KB -> 8 blocks/CU
  // diagonal iff this 64-col panel lies inside this 128-row band
  if ((blockIdx.x >> 1) == blockIdx.y)
    tile_body<true>(fn, pmask, nmask, pP, nP, cP, sim);
  else
    tile_body<false>(fn, pmask, nmask, pP, nP, cP, sim);
}

// ---------------------------------------------------------------------------
// Kernel 3a: reduce panels per row, per-row loss term, block sum -> blkSum[32]
// ---------------------------------------------------------------------------
__global__ __launch_bounds__(256) void finalize1(
    const float* __restrict__ pP, const float* __restrict__ nP,
    const float* __restrict__ cP, float* __restrict__ blkSum) {
  const int r = blockIdx.x * 256 + threadIdx.x;
  float p = 0.f, q = 0.f, c = 0.f;
#pragma unroll 4
  for (int k = 0; k < PANELS; ++k) {
    p += pP[(size_t)k * NN + r];
    q += nP[(size_t)k * NN + r];
    c += cP[(size_t)k * NN + r];
  }
  float s = logf(p / (p + q)) / c;
#pragma unroll
  for (int m = 1; m < 64; m <<= 1) s += __shfl_xor(s, m, 64);
  __shared__ float ws4[4];
  if ((threadIdx.x & 63) == 0) ws4[threadIdx.x >> 6] = s;
  __syncthreads();
  if (threadIdx.x == 0)
    blkSum[blockIdx.x] = ws4[0] + ws4[1] + ws4[2] + ws4[3];
}

// Kernel 3b: final 32-value sum -> loss
__global__ void finalize2(const float* __restrict__ blkSum,
                          float* __restrict__ out) {
  float s = (threadIdx.x < NN / 256) ? blkSum[threadIdx.x] : 0.f;
#pragma unroll
  for (int m = 1; m < 64; m <<= 1) s += __shfl_xor(s, m, 64);
  if (threadIdx.x == 0) out[0] = -s / (float)NN;
}

extern "C" void kernel_launch(void* const* d_in, const int* in_sizes, int n_in,
                              void* d_out, int out_size, void* d_ws, size_t ws_size,
                              hipStream_t stream) {
  const float* features = (const float*)d_in[0];
  const int* pmask = (const int*)d_in[1];
  const int* nmask = (const int*)d_in[2];
  float* out = (float*)d_out;

  char* ws = (char*)d_ws;
  __hip_bfloat16* fn = (__hip_bfloat16*)ws;  // 2 MB
  float* pP = (float*)(ws + (size_t)NN * DD * sizeof(__hip_bfloat16));
  float* nP = pP + (size_t)PANELS * NN;      // 3 x 4 MB panels
  float* cP = nP + (size_t)PANELS * NN;
  float* blkSum = cP + (size_t)PANELS * NN;  // 128 B

  normalize_kernel<<<NN / 4, 256, 0, stream>>>(features, fn);
  ssnt_main<<<dim3(NN / 64, NN / 128), 256, 0, stream>>>(fn, pmask, nmask,
                                                         pP, nP, cP);
  finalize1<<<NN / 256, 256, 0, stream>>>(pP, nP, cP, blkSum);
  finalize2<<<1, 64, 0, stream>>>(blkSum, out);
}

// Round 9
// 554.107 us; speedup vs baseline: 1.1239x; 1.0774x over previous
//
#include <hip/hip_runtime.h>
#include <hip/hip_bf16.h>
#include <stdint.h>
#include <stddef.h>

#define NN 8192
#define DD 128
#define PADW 136    // LDS row stride in bf16: 272 B, breaks phase-2/3 bank conflicts
#define PANELS 64   // one partial-sum panel per j-tile (grid.x)

typedef __attribute__((ext_vector_type(8))) short bf16x8;
typedef __attribute__((ext_vector_type(4))) float f32x4;

static __device__ __forceinline__ unsigned short f2bf(float x) {
  __hip_bfloat16 h = __float2bfloat16(x);
  return *(unsigned short*)&h;
}

// ---------------------------------------------------------------------------
// Kernel 1: row-normalize features (fp32) and cast to bf16. One wave per row.
// ---------------------------------------------------------------------------
__global__ __launch_bounds__(256) void normalize_kernel(
    const float* __restrict__ f, __hip_bfloat16* __restrict__ fn) {
  const int wave = threadIdx.x >> 6;
  const int lane = threadIdx.x & 63;
  const int row = blockIdx.x * 4 + wave;
  const float2 v = ((const float2*)(f + (size_t)row * DD))[lane];
  float ss = v.x * v.x + v.y * v.y;
#pragma unroll
  for (int m = 1; m < 64; m <<= 1) ss += __shfl_xor(ss, m, 64);
  const float inv = 1.0f / fmaxf(sqrtf(ss), 1e-8f);
  __hip_bfloat162 o;
  o.x = __float2bfloat16(v.x * inv);
  o.y = __float2bfloat16(v.y * inv);
  ((__hip_bfloat162*)(fn + (size_t)row * DD))[lane] = o;
}

// ---------------------------------------------------------------------------
// Phase-3 body with two-batch pipelined mask stream.
//   batch A (iters 0..3): prefetched BEFORE the barrier (caller), consumed
//   here while batch B (iters 4..7) loads are issued at the top of each
//   batch-A iteration — so every mask load has ≥1 full compute iteration
//   (plus the barrier, plus other warps' MFMA tails) of latency cover.
// All indices compile-time (full unroll) — no scratch (rule: runtime-indexed
// vector arrays spill).
// ---------------------------------------------------------------------------
template <bool DIAG, bool ATOMIC>
static __device__ __forceinline__ void phase3_run(
    const __hip_bfloat16* __restrict__ simc,  // sim + cl*8
    const int* __restrict__ pB, const int* __restrict__ nB,
    int4* __restrict__ pa, int4* __restrict__ pb,
    int4* __restrict__ na, int4* __restrict__ nb,  // prefetched iters 0..3
    int I0g, int J0g, int rGrp, int cl, int panelIdx,
    float* __restrict__ pP, float* __restrict__ nP, float* __restrict__ cP) {
  float accP[8], accQ[8], accC[8];

#pragma unroll
  for (int it = 0; it < 8; ++it) {
    // issue batch-B loads during batch-A compute (slots reused, static idx)
    if (it < 4) {
      const size_t off2 = (size_t)(it + 4) * 16 * NN;
      const int4 ta = *(const int4*)(pB + off2);
      const int4 tb = *(const int4*)(pB + off2 + 4);
      const int4 tc = *(const int4*)(nB + off2);
      const int4 td = *(const int4*)(nB + off2 + 4);
      // consume slot `it` (batch A), then refill it with batch B
      const int rLoc = it * 16 + rGrp;
      const bf16x8 ev = *(const bf16x8*)(simc + (size_t)rLoc * PADW);
      int pm8[8], nm8[8];
      *(int4*)&pm8[0] = pa[it]; *(int4*)&pm8[4] = pb[it];
      *(int4*)&nm8[0] = na[it]; *(int4*)&nm8[4] = nb[it];
      const int dj = DIAG ? ((I0g + rLoc) - (J0g + cl * 8)) : -1;
      float p = 0.f, q = 0.f;
      int c = 0;
#pragma unroll
      for (int r = 0; r < 8; ++r) {
        int pm = pm8[r];
        int nm = nm8[r];
        if (DIAG) {
          if (r == dj) { pm = 0; nm = 0; }  // zero self-contrast
        }
        const float e =
            __uint_as_float(((unsigned int)(unsigned short)ev[r]) << 16);
        p = fmaf(e, (float)pm, p);
        q = fmaf(e, (float)nm, q);
        c += pm;
      }
      accP[it] = p; accQ[it] = q; accC[it] = (float)c;
      pa[it] = ta; pb[it] = tb; na[it] = tc; nb[it] = td;
    } else {
      const int rLoc = it * 16 + rGrp;
      const bf16x8 ev = *(const bf16x8*)(simc + (size_t)rLoc * PADW);
      int pm8[8], nm8[8];
      *(int4*)&pm8[0] = pa[it - 4]; *(int4*)&pm8[4] = pb[it - 4];
      *(int4*)&nm8[0] = na[it - 4]; *(int4*)&nm8[4] = nb[it - 4];
      const int dj = DIAG ? ((I0g + rLoc) - (J0g + cl * 8)) : -1;
      float p = 0.f, q = 0.f;
      int c = 0;
#pragma unroll
      for (int r = 0; r < 8; ++r) {
        int pm = pm8[r];
        int nm = nm8[r];
        if (DIAG) {
          if (r == dj) { pm = 0; nm = 0; }
        }
        const float e =
            __uint_as_float(((unsigned int)(unsigned short)ev[r]) << 16);
        p = fmaf(e, (float)pm, p);
        q = fmaf(e, (float)nm, q);
        c += pm;
      }
      accP[it] = p; accQ[it] = q; accC[it] = (float)c;
    }
  }

  // ---- batched butterfly (24 independent chains), then output ----
#pragma unroll
  for (int m = 1; m < 16; m <<= 1) {
#pragma unroll
    for (int it = 0; it < 8; ++it) {
      accP[it] += __shfl_xor(accP[it], m, 64);
      accQ[it] += __shfl_xor(accQ[it], m, 64);
      accC[it] += __shfl_xor(accC[it], m, 64);
    }
  }
#pragma unroll
  for (int it = 0; it < 8; ++it) {
    const int iG = I0g + it * 16 + rGrp;
    if (ATOMIC) {
      if (cl == 0)      atomicAdd(&pP[iG], accP[it]);
      else if (cl == 1) atomicAdd(&nP[iG], accQ[it]);
      else if (cl == 2) atomicAdd(&cP[iG], accC[it]);
    } else {
      const size_t po = (size_t)panelIdx * NN + iG;
      if (cl == 0)      pP[po] = accP[it];
      else if (cl == 1) nP[po] = accQ[it];
      else if (cl == 2) cP[po] = accC[it];
    }
  }
}

// ---------------------------------------------------------------------------
// Kernel 2: one 128x128 sim tile per block (round-2 champion structure).
//   Phase 1: bf16 MFMA GEMM, fragments straight from L2 (fn is 2 MB).
//   Phase 2: exp(sim/T) -> LDS bf16.
//   Prefetch batch A of mask loads (acc regs dead; BEFORE the barrier, so
//   the barrier + other warps' MFMA tails hide the latency).
//   Phase 3: two-batch pipelined masked accumulation; deferred reduce.
// ---------------------------------------------------------------------------
template <bool ATOMIC>
__global__ __launch_bounds__(256, 4) void ssnt_main(
    const __hip_bfloat16* __restrict__ fn,
    const int* __restrict__ pmask,
    const int* __restrict__ nmask,
    float* __restrict__ pP, float* __restrict__ nP, float* __restrict__ cP) {
  __shared__ __hip_bfloat16 sim[128 * PADW];  // 34 KB -> 4 blocks/CU

  const int tid = threadIdx.x;
  const int lane = tid & 63;
  const int quad = lane >> 4;
  const int l16 = lane & 15;
  const int wx = (tid >> 6) & 1;
  const int wy = tid >> 7;
  const int rGrp = tid >> 4;  // phase-3 row group
  const int cl = tid & 15;    // phase-3 col group (8 cols each)

  const int I0g = blockIdx.y * 128;
  const int J0g = blockIdx.x * 128;
  const int I0 = I0g + wy * 64;
  const int J0 = J0g + wx * 64;

  // ---- Phase 1: GEMM ----
  f32x4 acc[4][4] = {};
#pragma unroll
  for (int kt = 0; kt < 4; ++kt) {
    const int ko = kt * 32 + quad * 8;
    bf16x8 aF[4], bF[4];
#pragma unroll
    for (int mt = 0; mt < 4; ++mt)
      aF[mt] = *(const bf16x8*)(fn + (size_t)(I0 + mt * 16 + l16) * DD + ko);
#pragma unroll
    for (int nt = 0; nt < 4; ++nt)
      bF[nt] = *(const bf16x8*)(fn + (size_t)(J0 + nt * 16 + l16) * DD + ko);
#pragma unroll
    for (int mt = 0; mt < 4; ++mt)
#pragma unroll
      for (int nt = 0; nt < 4; ++nt)
        acc[mt][nt] = __builtin_amdgcn_mfma_f32_16x16x32_bf16(
            bF[nt], aF[mt], acc[mt][nt], 0, 0, 0);  // SWAPPED operands
  }

  // ---- Phase 2: exp -> LDS (bf16) ----
  const float tinv = 1.0f / 0.07f;
#pragma unroll
  for (int mt = 0; mt < 4; ++mt) {
    const int iLoc = wy * 64 + mt * 16 + l16;
#pragma unroll
    for (int nt = 0; nt < 4; ++nt) {
      const int jLoc = wx * 64 + nt * 16 + quad * 4;
      ushort4 w;
      w.x = f2bf(__expf(acc[mt][nt][0] * tinv));
      w.y = f2bf(__expf(acc[mt][nt][1] * tinv));
      w.z = f2bf(__expf(acc[mt][nt][2] * tinv));
      w.w = f2bf(__expf(acc[mt][nt][3] * tinv));
      *(ushort4*)(sim + iLoc * PADW + jLoc) = w;
    }
  }

  // ---- Prefetch batch A (iters 0..3): acc is dead, 64-reg payload fits
  // the (256,4) 128-VGPR budget; latency hides under barrier + MFMA tails.
  const int* pB = pmask + (size_t)(I0g + rGrp) * NN + J0g + cl * 8;
  const int* nB = nmask + (size_t)(I0g + rGrp) * NN + J0g + cl * 8;
  int4 pa[4], pb[4], na[4], nb[4];
#pragma unroll
  for (int it = 0; it < 4; ++it) {
    const size_t off = (size_t)it * 16 * NN;
    pa[it] = *(const int4*)(pB + off);
    pb[it] = *(const int4*)(pB + off + 4);
    na[it] = *(const int4*)(nB + off);
    nb[it] = *(const int4*)(nB + off + 4);
  }

  __syncthreads();

  // ---- Phase 3 (block-uniform branch; barrier already passed) ----
  if (I0g == J0g)
    phase3_run<true, ATOMIC>(sim + cl * 8, pB, nB, pa, pb, na, nb,
                             I0g, J0g, rGrp, cl, blockIdx.x, pP, nP, cP);
  else
    phase3_run<false, ATOMIC>(sim + cl * 8, pB, nB, pa, pb, na, nb,
                              I0g, J0g, rGrp, cl, blockIdx.x, pP, nP, cP);
}

// ---------------------------------------------------------------------------
// Kernel 3a: reduce panels per row, per-row loss term, block sum -> blkSum[32]
// ---------------------------------------------------------------------------
__global__ __launch_bounds__(256) void finalize1(
    const float* __restrict__ pP, const float* __restrict__ nP,
    const float* __restrict__ cP, int panels, float* __restrict__ blkSum) {
  const int r = blockIdx.x * 256 + threadIdx.x;
  float p = 0.f, q = 0.f, c = 0.f;
  for (int k = 0; k < panels; ++k) {
    p += pP[(size_t)k * NN + r];
    q += nP[(size_t)k * NN + r];
    c += cP[(size_t)k * NN + r];
  }
  float s = logf(p / (p + q)) / c;
#pragma unroll
  for (int m = 1; m < 64; m <<= 1) s += __shfl_xor(s, m, 64);
  __shared__ float ws4[4];
  if ((threadIdx.x & 63) == 0) ws4[threadIdx.x >> 6] = s;
  __syncthreads();
  if (threadIdx.x == 0)
    blkSum[blockIdx.x] = ws4[0] + ws4[1] + ws4[2] + ws4[3];
}

// Kernel 3b: final 32-value sum -> loss
__global__ void finalize2(const float* __restrict__ blkSum,
                          float* __restrict__ out) {
  float s = (threadIdx.x < NN / 256) ? blkSum[threadIdx.x] : 0.f;
#pragma unroll
  for (int m = 1; m < 64; m <<= 1) s += __shfl_xor(s, m, 64);
  if (threadIdx.x == 0) out[0] = -s / (float)NN;
}

extern "C" void kernel_launch(void* const* d_in, const int* in_sizes, int n_in,
                              void* d_out, int out_size, void* d_ws, size_t ws_size,
                              hipStream_t stream) {
  const float* features = (const float*)d_in[0];
  const int* pmask = (const int*)d_in[1];
  const int* nmask = (const int*)d_in[2];
  float* out = (float*)d_out;

  char* ws = (char*)d_ws;
  __hip_bfloat16* fn = (__hip_bfloat16*)ws;  // 2 MB
  float* base = (float*)(ws + (size_t)NN * DD * sizeof(__hip_bfloat16));

  normalize_kernel<<<NN / 4, 256, 0, stream>>>(features, fn);

  const size_t needPanels =
      (size_t)NN * DD * 2 + 3ull * PANELS * NN * sizeof(float) + 256;
  if (ws_size >= needPanels) {
    // panel path: atomic-free, no memset
    float* pP = base;
    float* nP = pP + (size_t)PANELS * NN;
    float* cP = nP + (size_t)PANELS * NN;
    float* blkSum = cP + (size_t)PANELS * NN;
    ssnt_main<false><<<dim3(NN / 128, NN / 128), 256, 0, stream>>>(
        fn, pmask, nmask, pP, nP, cP);
    finalize1<<<NN / 256, 256, 0, stream>>>(pP, nP, cP, PANELS, blkSum);
    finalize2<<<1, 64, 0, stream>>>(blkSum, out);
  } else {
    // fallback: atomic accumulation into [NN] arrays
    float* pP = base;
    float* nP = pP + NN;
    float* cP = nP + NN;
    float* blkSum = cP + NN;
    hipMemsetAsync(pP, 0, 3 * (size_t)NN * sizeof(float), stream);
    ssnt_main<true><<<dim3(NN / 128, NN / 128), 256, 0, stream>>>(
        fn, pmask, nmask, pP, nP, cP);
    finalize1<<<NN / 256, 256, 0, stream>>>(pP, nP, cP, 1, blkSum);
    finalize2<<<1, 64, 0, stream>>>(blkSum, out);
  }
}